// Round 4
// baseline (1465.190 us; speedup 1.0000x reference)
//
#include <hip/hip_runtime.h>
#include <hip/hip_bf16.h>

#define H 2048
#define FDIM 1408
#define NE 64
#define CAP 512
#define NTOK 2048
#define FSH 2816

typedef float  f32x4  __attribute__((ext_vector_type(4)));
typedef short  s16x8  __attribute__((ext_vector_type(8)));
typedef unsigned short u16;
typedef u16    u16x4v __attribute__((ext_vector_type(4)));

__device__ __forceinline__ u16 f2bf(float f) {
    union { float f; unsigned u; } v; v.f = f;
    unsigned u = v.u;
    u += 0x7fffu + ((u >> 16) & 1u);
    return (u16)(u >> 16);
}
__device__ __forceinline__ float bf2f(u16 b) {
    union { unsigned u; float f; } v; v.u = ((unsigned)b) << 16;
    return v.f;
}
__device__ __forceinline__ void glds16(const u16* g, u16* l) {
    __builtin_amdgcn_global_load_lds(
        (const __attribute__((address_space(1))) unsigned int*)g,
        (__attribute__((address_space(3))) unsigned int*)l, 16, 0, 0);
}

#define WAIT_VM(N)  asm volatile("s_waitcnt vmcnt(" #N ")" ::: "memory")
#define WAIT_LGKM() asm volatile("s_waitcnt lgkmcnt(0)" ::: "memory")
#define SCHED_FENCE() __builtin_amdgcn_sched_barrier(0)

// ---------------- x fp32 -> bf16 once ----------------
__global__ __launch_bounds__(256) void xcvt(const float* __restrict__ x, u16* __restrict__ xb) {
    int i = blockIdx.x * 256 + threadIdx.x;
    const float4 a = ((const float4*)x)[2 * i];
    const float4 b = ((const float4*)x)[2 * i + 1];
    u16 v[8] = { f2bf(a.x), f2bf(a.y), f2bf(a.z), f2bf(a.w),
                 f2bf(b.x), f2bf(b.y), f2bf(b.z), f2bf(b.w) };
    *(s16x8*)(xb + (size_t)i * 8) = *(s16x8*)v;
}

// ---------------- init ----------------
__global__ void init_cnt(int* __restrict__ c) { c[threadIdx.x] = 0; }

// ---------------- gate: logits -> softmax -> top6 -> slot assign ----------------
__global__ __launch_bounds__(64) void gate_topk(
    const float* __restrict__ xg, const float* __restrict__ gw,
    int* __restrict__ cnt, int* __restrict__ tok_of,
    int* __restrict__ slot_enc, float* __restrict__ tw)
{
    const int t = blockIdx.x;
    const int lane = threadIdx.x;
    __shared__ float4 xs[512];
    const float4* xr = (const float4*)(xg + (size_t)t * H);
    #pragma unroll
    for (int i = 0; i < 8; ++i) xs[i * 64 + lane] = xr[i * 64 + lane];
    __syncthreads();

    const float4* gr = (const float4*)(gw + (size_t)lane * H);
    float acc = 0.f;
    #pragma unroll 4
    for (int i = 0; i < 512; ++i) {
        float4 a = xs[i], b = gr[i];
        acc += a.x * b.x + a.y * b.y + a.z * b.z + a.w * b.w;
    }
    float m = acc;
    #pragma unroll
    for (int off = 32; off; off >>= 1) m = fmaxf(m, __shfl_xor(m, off));
    float p = __expf(acc - m);
    float s = p;
    #pragma unroll
    for (int off = 32; off; off >>= 1) s += __shfl_xor(s, off);
    p = p / s;

    float myw = 0.f; int mye = 0;
    float v = p;
    for (int k = 0; k < 6; ++k) {
        float bv = v; int bi = lane;
        #pragma unroll
        for (int off = 32; off; off >>= 1) {
            float ov = __shfl_xor(bv, off);
            int   oi = __shfl_xor(bi, off);
            if (ov > bv || (ov == bv && oi < bi)) { bv = ov; bi = oi; }
        }
        if (lane == k)  { myw = bv; mye = bi; }
        if (lane == bi) v = -1.f;
    }
    if (lane < 6) {
        int slot = atomicAdd(&cnt[mye], 1);
        int enc = -1;
        if (slot < CAP) { tok_of[mye * CAP + slot] = t; enc = mye * CAP + slot; }
        slot_enc[t * 6 + lane] = enc;
        tw[t * 6 + lane] = myw;               // SCALE == 1.0
    }
}

// ---------------- fused gate+up grouped GEMM + SiLU ----------------
// BM=256, BN=32/mat, BK=64. A: global_load_lds (gathered, bf16). B: depth-2
// reg prefetch + end-of-iter LDS store. Counted vmcnt(4) barriers keep B in flight.
template<bool ROUTED>
__global__ __launch_bounds__(256, 2) void dual_gemm(
    const u16* __restrict__ xbf, const int* __restrict__ tok_of,
    const int* __restrict__ cnt_arr, const float* __restrict__ wg,
    const float* __restrict__ wu, u16* __restrict__ act, int Fd)
{
    __shared__ u16 As[2][8][256][8];      // 64 KB
    __shared__ u16 Bs[2][2][8][32][8];    // 16 KB

    int e = 0, cnt, m0, f0;
    if constexpr (ROUTED) {
        e = blockIdx.z;
        cnt = cnt_arr[e]; cnt = cnt < CAP ? cnt : CAP;
        f0 = blockIdx.x * 32; m0 = blockIdx.y * 256;
        if (m0 >= cnt) return;
    } else {
        cnt = NTOK;
        m0 = blockIdx.x * 256; f0 = blockIdx.y * 32;
    }

    const float* wg_e = wg;
    const float* wu_e = wu;
    u16* act_e = act;
    if constexpr (ROUTED) {
        wg_e += (size_t)e * H * Fd;
        wu_e += (size_t)e * H * Fd;
        act_e += (size_t)e * CAP * Fd;
    }

    const int tid = threadIdx.x;
    const int lane = tid & 63;
    const int wv = tid >> 6;
    const int NT = H / 64;

    // ---- A: per-lane gathered global source, wave-uniform LDS dest ----
    const u16* aptr;
    {
        int srow = m0 + tid;
        if constexpr (ROUTED) {
            const int* tok = tok_of + e * CAP;
            aptr = xbf + (size_t)tok[srow < cnt ? srow : 0] * H;
        } else {
            aptr = xbf + (size_t)srow * H;
        }
    }
    // ---- B geometry ----
    const int mat = tid >> 7;
    const int bb = tid & 127;
    const float* bsrc;
    int n4 = 0, kq = 0, br = 0, bc = 0;
    if constexpr (ROUTED) {
        n4 = bb & 7; kq = bb >> 3;                 // 4x4 transpose block
        bsrc = (mat ? wu_e : wg_e) + (size_t)(kq * 4) * Fd + f0 + n4 * 4;
    } else {
        br = bb >> 2; bc = bb & 3;                 // direct row
        bsrc = (mat ? wu_e : wg_e) + (size_t)(f0 + br) * H + bc * 16;
    }

    f32x4 bRa[4], bRb[4];
    f32x4 accg[4][2], accu[4][2];
    const f32x4 zero4 = {0.f, 0.f, 0.f, 0.f};
    #pragma unroll
    for (int i = 0; i < 4; ++i)
        #pragma unroll
        for (int j = 0; j < 2; ++j) { accg[i][j] = zero4; accu[i][j] = zero4; }

    auto GLDS_A = [&](int kt, int b) {
        #pragma unroll
        for (int q = 0; q < 8; ++q)
            glds16(aptr + kt * 64 + q * 8, &As[b][q][wv * 64][0]);
    };
    auto LOADB = [&](int kt, f32x4 (&dst)[4]) {
        if constexpr (ROUTED) {
            #pragma unroll
            for (int j = 0; j < 4; ++j)
                dst[j] = *(const f32x4*)(bsrc + ((size_t)kt * 64 + j) * Fd);
        } else {
            #pragma unroll
            for (int q = 0; q < 4; ++q)
                dst[q] = *(const f32x4*)(bsrc + kt * 64 + q * 4);
        }
    };
    auto STOREB = [&](const f32x4 (&src)[4], int b) {
        if constexpr (ROUTED) {
            const int k8 = kq >> 1, ko = (kq & 1) * 4;
            #pragma unroll
            for (int c = 0; c < 4; ++c) {
                u16x4v v; v[0] = f2bf(src[0][c]); v[1] = f2bf(src[1][c]);
                          v[2] = f2bf(src[2][c]); v[3] = f2bf(src[3][c]);
                *(u16x4v*)&Bs[b][mat][k8][(n4 * 4 + c) ^ k8][ko] = v;
            }
        } else {
            #pragma unroll
            for (int h = 0; h < 2; ++h) {
                const int k8 = bc * 2 + h;
                u16 v[8];
                f32x4 x0 = src[h * 2], x1 = src[h * 2 + 1];
                v[0]=f2bf(x0[0]); v[1]=f2bf(x0[1]); v[2]=f2bf(x0[2]); v[3]=f2bf(x0[3]);
                v[4]=f2bf(x1[0]); v[5]=f2bf(x1[1]); v[6]=f2bf(x1[2]); v[7]=f2bf(x1[3]);
                *(s16x8*)&Bs[b][mat][k8][br ^ k8][0] = *(s16x8*)v;
            }
        }
    };
    auto COMPUTE = [&](int b) {
        __builtin_amdgcn_s_setprio(1);
        #pragma unroll
        for (int kk = 0; kk < 2; ++kk) {
            const int k8 = kk * 4 + (lane >> 4);
            s16x8 a[4], bg[2], bu[2];
            #pragma unroll
            for (int mi = 0; mi < 4; ++mi)
                a[mi] = *(const s16x8*)&As[b][k8][wv * 64 + mi * 16 + (lane & 15)][0];
            #pragma unroll
            for (int ni = 0; ni < 2; ++ni) {
                const int np = (ni * 16 + (lane & 15)) ^ k8;
                bg[ni] = *(const s16x8*)&Bs[b][0][k8][np][0];
                bu[ni] = *(const s16x8*)&Bs[b][1][k8][np][0];
            }
            #pragma unroll
            for (int mi = 0; mi < 4; ++mi)
                #pragma unroll
                for (int ni = 0; ni < 2; ++ni) {
                    accg[mi][ni] = __builtin_amdgcn_mfma_f32_16x16x32_bf16(a[mi], bg[ni], accg[mi][ni], 0, 0, 0);
                    accu[mi][ni] = __builtin_amdgcn_mfma_f32_16x16x32_bf16(a[mi], bu[ni], accu[mi][ni], 0, 0, 0);
                }
        }
        __builtin_amdgcn_s_setprio(0);
    };

    // ---- prologue: A(0) via glds; B(0),B(1) to regs; store B(0) ----
    GLDS_A(0, 0);            SCHED_FENCE();
    LOADB(0, bRa);           SCHED_FENCE();
    LOADB(1, bRb);           SCHED_FENCE();
    WAIT_VM(4);                       // A(0)+B(0) done; B(1) in flight
    STOREB(bRa, 0);
    WAIT_LGKM();
    __builtin_amdgcn_s_barrier();
    SCHED_FENCE();

    for (int kt = 0; kt < NT; ++kt) {
        const int b = kt & 1;
        if (kt + 1 < NT) GLDS_A(kt + 1, b ^ 1);
        SCHED_FENCE();
        if ((kt & 1) == 0) { if (kt + 2 < NT) LOADB(kt + 2, bRa); }
        else               { if (kt + 2 < NT) LOADB(kt + 2, bRb); }
        SCHED_FENCE();
        COMPUTE(b);
        if (kt + 1 < NT) {
            if ((kt & 1) == 0) STOREB(bRb, b ^ 1);
            else               STOREB(bRa, b ^ 1);
        }
        if (kt + 2 < NT) { WAIT_VM(4); } else { WAIT_VM(0); }
        WAIT_LGKM();
        __builtin_amdgcn_s_barrier();
        SCHED_FENCE();
    }

    // ---- epilogue: silu(g)*u -> bf16 act ----
    #pragma unroll
    for (int mi = 0; mi < 4; ++mi)
        #pragma unroll
        for (int ni = 0; ni < 2; ++ni)
            #pragma unroll
            for (int r = 0; r < 4; ++r) {
                int srow = m0 + wv * 64 + mi * 16 + (lane >> 4) * 4 + r;
                if (srow < cnt) {
                    int fc = f0 + ni * 16 + (lane & 15);
                    float g = accg[mi][ni][r], u = accu[mi][ni][r];
                    float aa = (g / (1.f + __expf(-g))) * u;
                    act_e[(size_t)srow * Fd + fc] = f2bf(aa);
                }
            }
}

// ---------------- down-proj grouped GEMM ----------------
// BM=256, BN=64, BK=64. Same pipeline. ROUTED: A=act bf16, B=w_down [F][H]
// transpose-staged, out=dbuf bf16. !ROUTED: A=actsh, B=sh_down [H][FSH] direct, out=y fp32.
template<bool ROUTED>
__global__ __launch_bounds__(256, 2) void down_gemm(
    const u16* __restrict__ actA, const float* __restrict__ wdn,
    void* __restrict__ outp, const int* __restrict__ cnt_arr, int Kd)
{
    __shared__ u16 As[2][8][256][8];      // 64 KB
    __shared__ u16 Bs[2][8][64][8];       // 16 KB

    int e = 0, cnt, m0, n0;
    if constexpr (ROUTED) {
        e = blockIdx.z;
        cnt = cnt_arr[e]; cnt = cnt < CAP ? cnt : CAP;
        n0 = blockIdx.x * 64; m0 = blockIdx.y * 256;
        if (m0 >= cnt) return;
    } else {
        cnt = NTOK;
        m0 = blockIdx.x * 256; n0 = blockIdx.y * 64;
    }

    const u16* A_e = actA;
    const float* B_e = wdn;
    if constexpr (ROUTED) {
        A_e += (size_t)e * CAP * Kd;
        B_e += (size_t)e * Kd * H;
    }
    const int NT = Kd / 64;
    const int tid = threadIdx.x, lane = tid & 63, wv = tid >> 6;

    const u16* aptr = A_e + (size_t)(m0 + tid) * Kd;

    const float* bsrc;
    int n4 = 0, kq = 0, dr = 0, dc = 0;
    if constexpr (ROUTED) {
        n4 = tid & 15; kq = tid >> 4;
        bsrc = B_e + (size_t)(kq * 4) * H + n0 + n4 * 4;
    } else {
        dr = tid >> 2; dc = tid & 3;
        bsrc = B_e + (size_t)(n0 + dr) * FSH + dc * 16;
    }

    f32x4 bRa[4], bRb[4];
    f32x4 acc[4][4];
    const f32x4 zero4 = {0.f, 0.f, 0.f, 0.f};
    #pragma unroll
    for (int i = 0; i < 4; ++i)
        #pragma unroll
        for (int j = 0; j < 4; ++j) acc[i][j] = zero4;

    auto GLDS_A = [&](int kt, int b) {
        #pragma unroll
        for (int q = 0; q < 8; ++q)
            glds16(aptr + kt * 64 + q * 8, &As[b][q][wv * 64][0]);
    };
    auto LOADB = [&](int kt, f32x4 (&dst)[4]) {
        if constexpr (ROUTED) {
            #pragma unroll
            for (int j = 0; j < 4; ++j)
                dst[j] = *(const f32x4*)(bsrc + ((size_t)kt * 64 + j) * H);
        } else {
            #pragma unroll
            for (int q = 0; q < 4; ++q)
                dst[q] = *(const f32x4*)(bsrc + kt * 64 + q * 4);
        }
    };
    auto STOREB = [&](const f32x4 (&src)[4], int b) {
        if constexpr (ROUTED) {
            const int k8 = kq >> 1, ko = (kq & 1) * 4;
            #pragma unroll
            for (int c = 0; c < 4; ++c) {
                u16x4v v; v[0] = f2bf(src[0][c]); v[1] = f2bf(src[1][c]);
                          v[2] = f2bf(src[2][c]); v[3] = f2bf(src[3][c]);
                *(u16x4v*)&Bs[b][k8][(n4 * 4 + c) ^ k8][ko] = v;
            }
        } else {
            #pragma unroll
            for (int h = 0; h < 2; ++h) {
                const int k8 = dc * 2 + h;
                u16 v[8];
                f32x4 x0 = src[h * 2], x1 = src[h * 2 + 1];
                v[0]=f2bf(x0[0]); v[1]=f2bf(x0[1]); v[2]=f2bf(x0[2]); v[3]=f2bf(x0[3]);
                v[4]=f2bf(x1[0]); v[5]=f2bf(x1[1]); v[6]=f2bf(x1[2]); v[7]=f2bf(x1[3]);
                *(s16x8*)&Bs[b][k8][dr ^ k8][0] = *(s16x8*)v;
            }
        }
    };
    auto COMPUTE = [&](int b) {
        __builtin_amdgcn_s_setprio(1);
        #pragma unroll
        for (int kk = 0; kk < 2; ++kk) {
            const int k8 = kk * 4 + (lane >> 4);
            s16x8 a[4], bf[4];
            #pragma unroll
            for (int mi = 0; mi < 4; ++mi)
                a[mi] = *(const s16x8*)&As[b][k8][wv * 64 + mi * 16 + (lane & 15)][0];
            #pragma unroll
            for (int ni = 0; ni < 4; ++ni)
                bf[ni] = *(const s16x8*)&Bs[b][k8][(ni * 16 + (lane & 15)) ^ k8][0];
            #pragma unroll
            for (int mi = 0; mi < 4; ++mi)
                #pragma unroll
                for (int ni = 0; ni < 4; ++ni)
                    acc[mi][ni] = __builtin_amdgcn_mfma_f32_16x16x32_bf16(a[mi], bf[ni], acc[mi][ni], 0, 0, 0);
        }
        __builtin_amdgcn_s_setprio(0);
    };

    GLDS_A(0, 0);            SCHED_FENCE();
    LOADB(0, bRa);           SCHED_FENCE();
    LOADB(1, bRb);           SCHED_FENCE();
    WAIT_VM(4);
    STOREB(bRa, 0);
    WAIT_LGKM();
    __builtin_amdgcn_s_barrier();
    SCHED_FENCE();

    for (int kt = 0; kt < NT; ++kt) {
        const int b = kt & 1;
        if (kt + 1 < NT) GLDS_A(kt + 1, b ^ 1);
        SCHED_FENCE();
        if ((kt & 1) == 0) { if (kt + 2 < NT) LOADB(kt + 2, bRa); }
        else               { if (kt + 2 < NT) LOADB(kt + 2, bRb); }
        SCHED_FENCE();
        COMPUTE(b);
        if (kt + 1 < NT) {
            if ((kt & 1) == 0) STOREB(bRb, b ^ 1);
            else               STOREB(bRa, b ^ 1);
        }
        if (kt + 2 < NT) { WAIT_VM(4); } else { WAIT_VM(0); }
        WAIT_LGKM();
        __builtin_amdgcn_s_barrier();
        SCHED_FENCE();
    }

    #pragma unroll
    for (int mi = 0; mi < 4; ++mi)
        #pragma unroll
        for (int ni = 0; ni < 4; ++ni)
            #pragma unroll
            for (int r = 0; r < 4; ++r) {
                int srow = m0 + wv * 64 + mi * 16 + (lane >> 4) * 4 + r;
                if (srow < cnt) {
                    int col = n0 + ni * 16 + (lane & 15);
                    float vv = acc[mi][ni][r];
                    if constexpr (ROUTED)
                        ((u16*)outp)[(size_t)e * CAP * H + (size_t)srow * H + col] = f2bf(vv);
                    else
                        ((float*)outp)[(size_t)srow * H + col] = vv;
                }
            }
}

// ---------------- combine: y += sum_k w_k * d[enc_k] ----------------
__global__ __launch_bounds__(256) void combine(
    float* __restrict__ y, const u16* __restrict__ d,
    const int* __restrict__ slot_enc, const float* __restrict__ tw)
{
    const int t = blockIdx.x, tid = threadIdx.x;
    int enc[6]; float w[6];
    #pragma unroll
    for (int k = 0; k < 6; ++k) {
        enc[k] = slot_enc[t * 6 + k];
        w[k] = tw[t * 6 + k];
    }
    float4* yrow = (float4*)(y + (size_t)t * H);
    #pragma unroll
    for (int it = 0; it < 2; ++it) {
        int h4 = it * 256 + tid;
        float4 acc = yrow[h4];
        #pragma unroll
        for (int k = 0; k < 6; ++k) {
            if (enc[k] >= 0) {
                ushort4 dv = ((const ushort4*)(d + (size_t)enc[k] * H))[h4];
                acc.x += w[k] * bf2f(dv.x);
                acc.y += w[k] * bf2f(dv.y);
                acc.z += w[k] * bf2f(dv.z);
                acc.w += w[k] * bf2f(dv.w);
            }
        }
        yrow[h4] = acc;
    }
}

extern "C" void kernel_launch(void* const* d_in, const int* in_sizes, int n_in,
                              void* d_out, int out_size, void* d_ws, size_t ws_size,
                              hipStream_t stream) {
    const float* x       = (const float*)d_in[0];
    const float* gw      = (const float*)d_in[1];
    const float* w_gate  = (const float*)d_in[2];
    const float* w_up    = (const float*)d_in[3];
    const float* w_down  = (const float*)d_in[4];
    const float* sh_gate = (const float*)d_in[5];
    const float* sh_up   = (const float*)d_in[6];
    const float* sh_down = (const float*)d_in[7];
    float* y = (float*)d_out;

    char* wsb = (char*)d_ws;
    int*   cnt      = (int*)(wsb + 0);                       // 64 ints
    int*   tok_of   = (int*)(wsb + 512);                     // 64*512 ints
    int*   slot_enc = (int*)(wsb + 512 + 131072);            // 2048*6 ints
    float* tw       = (float*)(wsb + 512 + 131072 + 49152);  // 2048*6 floats
    u16*   act      = (u16*)(wsb + 230144);                  // 64*512*1408 bf16
    u16*   actsh    = (u16*)(wsb + 230144 + 92274688);       // 2048*2816 bf16
    u16*   dbuf     = (u16*)(wsb + 230144 + 92274688 + 11534336); // 64*512*2048 bf16
    u16*   xbf      = dbuf;  // alias: xbf (8MB) dead before down_gemm writes dbuf

    init_cnt<<<1, 64, 0, stream>>>(cnt);
    xcvt<<<NTOK * H / 8 / 256, 256, 0, stream>>>(x, xbf);
    gate_topk<<<NTOK, 64, 0, stream>>>(x, gw, cnt, tok_of, slot_enc, tw);
    dual_gemm<true><<<dim3(FDIM / 32, 2, NE), 256, 0, stream>>>(
        xbf, tok_of, cnt, w_gate, w_up, act, FDIM);
    dual_gemm<false><<<dim3(NTOK / 256, FSH / 32, 1), 256, 0, stream>>>(
        xbf, nullptr, nullptr, sh_gate, sh_up, actsh, FSH);
    down_gemm<true><<<dim3(H / 64, 2, NE), 256, 0, stream>>>(
        act, w_down, (void*)dbuf, cnt, FDIM);
    down_gemm<false><<<dim3(NTOK / 256, H / 64, 1), 256, 0, stream>>>(
        actsh, sh_down, (void*)y, nullptr, FSH);
    combine<<<NTOK, 256, 0, stream>>>(y, dbuf, slot_enc, tw);
}

// Round 5
// 1327.844 us; speedup vs baseline: 1.1034x; 1.1034x over previous
//
#include <hip/hip_runtime.h>
#include <hip/hip_bf16.h>

#define H 2048
#define FDIM 1408
#define NE 64
#define CAP 512
#define NTOK 2048
#define FSH 2816

typedef float  f32x4  __attribute__((ext_vector_type(4)));
typedef short  s16x8  __attribute__((ext_vector_type(8)));
typedef unsigned short u16;
typedef u16    u16x4v __attribute__((ext_vector_type(4)));

__device__ __forceinline__ u16 f2bf(float f) {
    union { float f; unsigned u; } v; v.f = f;
    unsigned u = v.u;
    u += 0x7fffu + ((u >> 16) & 1u);
    return (u16)(u >> 16);
}
__device__ __forceinline__ float bf2f(u16 b) {
    union { unsigned u; float f; } v; v.u = ((unsigned)b) << 16;
    return v.f;
}
// element-granular XOR swizzle (multiples of 8 elems = 16B) within 64-elem rows
__device__ __forceinline__ int swze(int row) {
    return (((row & 7) ^ ((row >> 3) & 7)) << 3);
}
__device__ __forceinline__ void wr4(u16* dst, float a, float b, float c, float d) {
    u16x4v v; v[0] = f2bf(a); v[1] = f2bf(b); v[2] = f2bf(c); v[3] = f2bf(d);
    *(u16x4v*)dst = v;
}

// barrier that does NOT drain vmcnt: LDS ordered, global loads stay in flight
#define BAR() do { asm volatile("s_waitcnt lgkmcnt(0)" ::: "memory"); \
                   __builtin_amdgcn_s_barrier(); } while (0)
#define SCHED_FENCE() __builtin_amdgcn_sched_barrier(0)

// ---------------- x fp32 -> bf16 once ----------------
__global__ __launch_bounds__(256) void xcvt(const float* __restrict__ x, u16* __restrict__ xb) {
    int i = blockIdx.x * 256 + threadIdx.x;
    const float4 a = ((const float4*)x)[2 * i];
    const float4 b = ((const float4*)x)[2 * i + 1];
    u16 v[8] = { f2bf(a.x), f2bf(a.y), f2bf(a.z), f2bf(a.w),
                 f2bf(b.x), f2bf(b.y), f2bf(b.z), f2bf(b.w) };
    *(s16x8*)(xb + (size_t)i * 8) = *(s16x8*)v;
}

// ---------------- init ----------------
__global__ void init_cnt(int* __restrict__ c) { c[threadIdx.x] = 0; }

// ---------------- gate: logits -> softmax -> top6 -> slot assign ----------------
__global__ __launch_bounds__(64) void gate_topk(
    const float* __restrict__ xg, const float* __restrict__ gw,
    int* __restrict__ cnt, int* __restrict__ tok_of,
    int* __restrict__ slot_enc, float* __restrict__ tw)
{
    const int t = blockIdx.x;
    const int lane = threadIdx.x;
    __shared__ float4 xs[512];
    const float4* xr = (const float4*)(xg + (size_t)t * H);
    #pragma unroll
    for (int i = 0; i < 8; ++i) xs[i * 64 + lane] = xr[i * 64 + lane];
    __syncthreads();

    const float4* gr = (const float4*)(gw + (size_t)lane * H);
    float acc = 0.f;
    #pragma unroll 4
    for (int i = 0; i < 512; ++i) {
        float4 a = xs[i], b = gr[i];
        acc += a.x * b.x + a.y * b.y + a.z * b.z + a.w * b.w;
    }
    float m = acc;
    #pragma unroll
    for (int off = 32; off; off >>= 1) m = fmaxf(m, __shfl_xor(m, off));
    float p = __expf(acc - m);
    float s = p;
    #pragma unroll
    for (int off = 32; off; off >>= 1) s += __shfl_xor(s, off);
    p = p / s;

    float myw = 0.f; int mye = 0;
    float v = p;
    for (int k = 0; k < 6; ++k) {
        float bv = v; int bi = lane;
        #pragma unroll
        for (int off = 32; off; off >>= 1) {
            float ov = __shfl_xor(bv, off);
            int   oi = __shfl_xor(bi, off);
            if (ov > bv || (ov == bv && oi < bi)) { bv = ov; bi = oi; }
        }
        if (lane == k)  { myw = bv; mye = bi; }
        if (lane == bi) v = -1.f;
    }
    if (lane < 6) {
        int slot = atomicAdd(&cnt[mye], 1);
        int enc = -1;
        if (slot < CAP) { tok_of[mye * CAP + slot] = t; enc = mye * CAP + slot; }
        slot_enc[t * 6 + lane] = enc;
        tw[t * 6 + lane] = myw;               // SCALE == 1.0
    }
}

// ---------------- fused gate+up grouped GEMM + SiLU ----------------
// BM=256, BN=32/mat, BK=64. Round-2 lane/LDS geometry; dual reg sets give
// loads ~2 iterations of latency cover; barriers never drain vmcnt.
template<bool ROUTED>
__global__ __launch_bounds__(256, 2) void dual_gemm(
    const u16* __restrict__ xbf, const int* __restrict__ tok_of,
    const int* __restrict__ cnt_arr, const float* __restrict__ wg,
    const float* __restrict__ wu, u16* __restrict__ act, int Fd)
{
    __shared__ u16 As[2][256 * 64];       // 64 KB
    __shared__ u16 Bgs[2][32 * 64];       // 8 KB
    __shared__ u16 Bus[2][32 * 64];       // 8 KB

    int e = 0, cnt, m0, f0;
    if constexpr (ROUTED) {
        e = blockIdx.z;
        cnt = cnt_arr[e]; cnt = cnt < CAP ? cnt : CAP;
        f0 = blockIdx.x * 32; m0 = blockIdx.y * 256;
        if (m0 >= cnt) return;
    } else {
        cnt = NTOK;
        m0 = blockIdx.x * 256; f0 = blockIdx.y * 32;
    }

    const float* wg_e = wg;
    const float* wu_e = wu;
    u16* act_e = act;
    if constexpr (ROUTED) {
        wg_e += (size_t)e * H * Fd;
        wu_e += (size_t)e * H * Fd;
        act_e += (size_t)e * CAP * Fd;
    }

    const int tid = threadIdx.x;
    const int lane = tid & 63;
    const int wv = tid >> 6;
    const int NT = H / 64;                // 32, even

    // ---- A geometry (round-2): 8 lanes per row-chunk, coalesced 128B ----
    const int ac = tid & 7;
    int arl[8];
    const u16* arow[8];
    #pragma unroll
    for (int it = 0; it < 8; ++it) {
        int row = it * 32 + (tid >> 3);
        arl[it] = row;
        int srow = m0 + row;
        if constexpr (ROUTED) {
            const int* tok = tok_of + e * CAP;
            arow[it] = xbf + (size_t)tok[srow < cnt ? srow : 0] * H;
        } else {
            arow[it] = xbf + (size_t)srow * H;
        }
    }
    // ---- B geometry ----
    const int mat = tid >> 7;
    const int bb = tid & 127;
    const float* bsrc;
    int bn4 = 0, bkb = 0, br = 0, bc = 0;
    if constexpr (ROUTED) {
        bn4 = bb & 7; bkb = bb >> 3;               // 4x4 transpose block
        bsrc = (mat ? wu_e : wg_e) + (size_t)(bkb * 4) * Fd + f0 + bn4 * 4;
    } else {
        br = bb >> 2; bc = bb & 3;                 // direct row, 16 floats/thread
        bsrc = (mat ? wu_e : wg_e) + (size_t)(f0 + br) * H + bc * 16;
    }

    f32x4 accg[4][2], accu[4][2];
    const f32x4 zero4 = {0.f, 0.f, 0.f, 0.f};
    #pragma unroll
    for (int i = 0; i < 4; ++i)
        #pragma unroll
        for (int j = 0; j < 2; ++j) { accg[i][j] = zero4; accu[i][j] = zero4; }

    s16x8 aR0[8], aR1[8];
    f32x4 bR0[4], bR1[4];

    auto LOADA = [&](int kt, s16x8 (&ar)[8]) {
        #pragma unroll
        for (int it = 0; it < 8; ++it)
            ar[it] = *(const s16x8*)(arow[it] + kt * 64 + ac * 8);
    };
    auto LOADB = [&](int kt, f32x4 (&brg)[4]) {
        if constexpr (ROUTED) {
            #pragma unroll
            for (int j = 0; j < 4; ++j)
                brg[j] = *(const f32x4*)(bsrc + ((size_t)kt * 64 + j) * Fd);
        } else {
            #pragma unroll
            for (int q = 0; q < 4; ++q)
                brg[q] = *(const f32x4*)(bsrc + kt * 64 + q * 4);
        }
    };
    auto STORE = [&](const s16x8 (&ar)[8], const f32x4 (&brg)[4], int b) {
        #pragma unroll
        for (int it = 0; it < 8; ++it)
            *(s16x8*)&As[b][arl[it] * 64 + ((ac * 8) ^ swze(arl[it]))] = ar[it];
        u16* Bdst = mat ? Bus[b] : Bgs[b];
        if constexpr (ROUTED) {
            #pragma unroll
            for (int j = 0; j < 4; ++j) {
                int rr = bn4 * 4 + j;
                wr4(&Bdst[rr * 64 + ((bkb * 4) ^ swze(rr))],
                    brg[0][j], brg[1][j], brg[2][j], brg[3][j]);
            }
        } else {
            #pragma unroll
            for (int q = 0; q < 4; ++q)
                wr4(&Bdst[br * 64 + (((bc * 16 + q * 4)) ^ swze(br))],
                    brg[q].x, brg[q].y, brg[q].z, brg[q].w);
        }
    };
    auto COMPUTE = [&](int b) {
        __builtin_amdgcn_s_setprio(1);
        #pragma unroll
        for (int kk = 0; kk < 2; ++kk) {
            const int ko = kk * 32 + (lane >> 4) * 8;
            s16x8 a[4], bg[2], bu[2];
            #pragma unroll
            for (int mi = 0; mi < 4; ++mi) {
                int r = wv * 64 + mi * 16 + (lane & 15);
                a[mi] = *(const s16x8*)&As[b][r * 64 + (ko ^ swze(r))];
            }
            #pragma unroll
            for (int ni = 0; ni < 2; ++ni) {
                int r = ni * 16 + (lane & 15);
                bg[ni] = *(const s16x8*)&Bgs[b][r * 64 + (ko ^ swze(r))];
                bu[ni] = *(const s16x8*)&Bus[b][r * 64 + (ko ^ swze(r))];
            }
            #pragma unroll
            for (int mi = 0; mi < 4; ++mi)
                #pragma unroll
                for (int ni = 0; ni < 2; ++ni) {
                    accg[mi][ni] = __builtin_amdgcn_mfma_f32_16x16x32_bf16(a[mi], bg[ni], accg[mi][ni], 0, 0, 0);
                    accu[mi][ni] = __builtin_amdgcn_mfma_f32_16x16x32_bf16(a[mi], bu[ni], accu[mi][ni], 0, 0, 0);
                }
        }
        __builtin_amdgcn_s_setprio(0);
    };

    // ---- prologue: tiles 0,1 to regs; tile0 -> LDS; tile2 to regs ----
    LOADB(0, bR0); LOADA(0, aR0);
    LOADB(1, bR1); LOADA(1, aR1);
    STORE(aR0, bR0, 0);                 // auto-counted vmcnt wait on tile 0
    LOADB(2, bR0); LOADA(2, aR0);
    BAR(); SCHED_FENCE();

    // invariant at top of iter kt: buf kt&1 = tile kt ready;
    // S[(kt+1)&1] = tile kt+1 (regs); S[(kt)&1] = tile kt+2 (in flight/regs)
    for (int kt = 0; kt < NT; kt += 2) {
        // even: read buf0, fill buf1 from set1 (tile kt+1), load kt+3 -> set1
        STORE(aR1, bR1, 1);
        if (kt + 3 < NT) { LOADB(kt + 3, bR1); LOADA(kt + 3, aR1); }
        SCHED_FENCE();
        COMPUTE(0);
        BAR(); SCHED_FENCE();
        // odd: read buf1, fill buf0 from set0 (tile kt+2), load kt+4 -> set0
        if (kt + 2 < NT) {
            STORE(aR0, bR0, 0);
            if (kt + 4 < NT) { LOADB(kt + 4, bR0); LOADA(kt + 4, aR0); }
        }
        SCHED_FENCE();
        COMPUTE(1);
        BAR(); SCHED_FENCE();
    }

    // ---- epilogue: silu(g)*u -> bf16 act (linear layout) ----
    #pragma unroll
    for (int mi = 0; mi < 4; ++mi)
        #pragma unroll
        for (int ni = 0; ni < 2; ++ni)
            #pragma unroll
            for (int r = 0; r < 4; ++r) {
                int srow = m0 + wv * 64 + mi * 16 + (lane >> 4) * 4 + r;
                if (srow < cnt) {
                    int fc = f0 + ni * 16 + (lane & 15);
                    float g = accg[mi][ni][r], u = accu[mi][ni][r];
                    float aa = (g / (1.f + __expf(-g))) * u;
                    act_e[(size_t)srow * Fd + fc] = f2bf(aa);
                }
            }
}

// ---------------- down-proj grouped GEMM ----------------
// BM=256, BN=64, BK=64. Same pipeline. ROUTED: A=act bf16 (linear), B=w_down
// [F][H] transpose-staged, out=dbuf bf16. !ROUTED: B=sh_down [H][FSH] direct, out=y fp32.
template<bool ROUTED>
__global__ __launch_bounds__(256, 2) void down_gemm(
    const u16* __restrict__ actA, const float* __restrict__ wdn,
    void* __restrict__ outp, const int* __restrict__ cnt_arr, int Kd)
{
    __shared__ u16 As[2][256 * 64];       // 64 KB
    __shared__ u16 Bs[2][64 * 64];        // 16 KB

    int e = 0, cnt, m0, n0;
    if constexpr (ROUTED) {
        e = blockIdx.z;
        cnt = cnt_arr[e]; cnt = cnt < CAP ? cnt : CAP;
        n0 = blockIdx.x * 64; m0 = blockIdx.y * 256;
        if (m0 >= cnt) return;
    } else {
        cnt = NTOK;
        m0 = blockIdx.x * 256; n0 = blockIdx.y * 64;
    }

    const u16* A_e = actA;
    const float* B_e = wdn;
    if constexpr (ROUTED) {
        A_e += (size_t)e * CAP * Kd;
        B_e += (size_t)e * Kd * H;
    }
    const int NT = Kd / 64;               // 22 or 44/32: even
    const int tid = threadIdx.x, lane = tid & 63, wv = tid >> 6;

    const int ac = tid & 7;
    int arl[8];
    const u16* arow[8];
    #pragma unroll
    for (int it = 0; it < 8; ++it) {
        int row = it * 32 + (tid >> 3);
        arl[it] = row;
        arow[it] = A_e + (size_t)(m0 + row) * Kd;
    }
    const float* bsrc;
    int bn4 = 0, bkq = 0, dr = 0, dc = 0;
    if constexpr (ROUTED) {
        bn4 = tid & 15; bkq = tid >> 4;
        bsrc = B_e + (size_t)(bkq * 4) * H + n0 + bn4 * 4;
    } else {
        dr = tid >> 2; dc = tid & 3;
        bsrc = B_e + (size_t)(n0 + dr) * FSH + dc * 16;
    }

    f32x4 acc[4][4];
    const f32x4 zero4 = {0.f, 0.f, 0.f, 0.f};
    #pragma unroll
    for (int i = 0; i < 4; ++i)
        #pragma unroll
        for (int j = 0; j < 4; ++j) acc[i][j] = zero4;

    s16x8 aR0[8], aR1[8];
    f32x4 bR0[4], bR1[4];

    auto LOADA = [&](int kt, s16x8 (&ar)[8]) {
        #pragma unroll
        for (int it = 0; it < 8; ++it)
            ar[it] = *(const s16x8*)(arow[it] + kt * 64 + ac * 8);
    };
    auto LOADB = [&](int kt, f32x4 (&brg)[4]) {
        if constexpr (ROUTED) {
            #pragma unroll
            for (int j = 0; j < 4; ++j)
                brg[j] = *(const f32x4*)(bsrc + ((size_t)kt * 64 + j) * H);
        } else {
            #pragma unroll
            for (int q = 0; q < 4; ++q)
                brg[q] = *(const f32x4*)(bsrc + kt * 64 + q * 4);
        }
    };
    auto STORE = [&](const s16x8 (&ar)[8], const f32x4 (&brg)[4], int b) {
        #pragma unroll
        for (int it = 0; it < 8; ++it)
            *(s16x8*)&As[b][arl[it] * 64 + ((ac * 8) ^ swze(arl[it]))] = ar[it];
        if constexpr (ROUTED) {
            #pragma unroll
            for (int j = 0; j < 4; ++j) {
                int rr = bn4 * 4 + j;
                wr4(&Bs[b][rr * 64 + ((bkq * 4) ^ swze(rr))],
                    brg[0][j], brg[1][j], brg[2][j], brg[3][j]);
            }
        } else {
            #pragma unroll
            for (int q = 0; q < 4; ++q)
                wr4(&Bs[b][dr * 64 + (((dc * 16 + q * 4)) ^ swze(dr))],
                    brg[q].x, brg[q].y, brg[q].z, brg[q].w);
        }
    };
    auto COMPUTE = [&](int b) {
        __builtin_amdgcn_s_setprio(1);
        #pragma unroll
        for (int kk = 0; kk < 2; ++kk) {
            const int ko = kk * 32 + (lane >> 4) * 8;
            s16x8 a[4], bf[4];
            #pragma unroll
            for (int mi = 0; mi < 4; ++mi) {
                int r = wv * 64 + mi * 16 + (lane & 15);
                a[mi] = *(const s16x8*)&As[b][r * 64 + (ko ^ swze(r))];
            }
            #pragma unroll
            for (int ni = 0; ni < 4; ++ni) {
                int r = ni * 16 + (lane & 15);
                bf[ni] = *(const s16x8*)&Bs[b][r * 64 + (ko ^ swze(r))];
            }
            #pragma unroll
            for (int mi = 0; mi < 4; ++mi)
                #pragma unroll
                for (int ni = 0; ni < 4; ++ni)
                    acc[mi][ni] = __builtin_amdgcn_mfma_f32_16x16x32_bf16(a[mi], bf[ni], acc[mi][ni], 0, 0, 0);
        }
        __builtin_amdgcn_s_setprio(0);
    };

    LOADB(0, bR0); LOADA(0, aR0);
    LOADB(1, bR1); LOADA(1, aR1);
    STORE(aR0, bR0, 0);
    LOADB(2, bR0); LOADA(2, aR0);
    BAR(); SCHED_FENCE();

    for (int kt = 0; kt < NT; kt += 2) {
        STORE(aR1, bR1, 1);
        if (kt + 3 < NT) { LOADB(kt + 3, bR1); LOADA(kt + 3, aR1); }
        SCHED_FENCE();
        COMPUTE(0);
        BAR(); SCHED_FENCE();
        if (kt + 2 < NT) {
            STORE(aR0, bR0, 0);
            if (kt + 4 < NT) { LOADB(kt + 4, bR0); LOADA(kt + 4, aR0); }
        }
        SCHED_FENCE();
        COMPUTE(1);
        BAR(); SCHED_FENCE();
    }

    #pragma unroll
    for (int mi = 0; mi < 4; ++mi)
        #pragma unroll
        for (int ni = 0; ni < 4; ++ni)
            #pragma unroll
            for (int r = 0; r < 4; ++r) {
                int srow = m0 + wv * 64 + mi * 16 + (lane >> 4) * 4 + r;
                if (srow < cnt) {
                    int col = n0 + ni * 16 + (lane & 15);
                    float vv = acc[mi][ni][r];
                    if constexpr (ROUTED)
                        ((u16*)outp)[(size_t)e * CAP * H + (size_t)srow * H + col] = f2bf(vv);
                    else
                        ((float*)outp)[(size_t)srow * H + col] = vv;
                }
            }
}

// ---------------- combine: y += sum_k w_k * d[enc_k] ----------------
__global__ __launch_bounds__(256) void combine(
    float* __restrict__ y, const u16* __restrict__ d,
    const int* __restrict__ slot_enc, const float* __restrict__ tw)
{
    const int t = blockIdx.x, tid = threadIdx.x;
    int enc[6]; float w[6];
    #pragma unroll
    for (int k = 0; k < 6; ++k) {
        enc[k] = slot_enc[t * 6 + k];
        w[k] = tw[t * 6 + k];
    }
    float4* yrow = (float4*)(y + (size_t)t * H);
    #pragma unroll
    for (int it = 0; it < 2; ++it) {
        int h4 = it * 256 + tid;
        float4 acc = yrow[h4];
        #pragma unroll
        for (int k = 0; k < 6; ++k) {
            if (enc[k] >= 0) {
                ushort4 dv = ((const ushort4*)(d + (size_t)enc[k] * H))[h4];
                acc.x += w[k] * bf2f(dv.x);
                acc.y += w[k] * bf2f(dv.y);
                acc.z += w[k] * bf2f(dv.z);
                acc.w += w[k] * bf2f(dv.w);
            }
        }
        yrow[h4] = acc;
    }
}

extern "C" void kernel_launch(void* const* d_in, const int* in_sizes, int n_in,
                              void* d_out, int out_size, void* d_ws, size_t ws_size,
                              hipStream_t stream) {
    const float* x       = (const float*)d_in[0];
    const float* gw      = (const float*)d_in[1];
    const float* w_gate  = (const float*)d_in[2];
    const float* w_up    = (const float*)d_in[3];
    const float* w_down  = (const float*)d_in[4];
    const float* sh_gate = (const float*)d_in[5];
    const float* sh_up   = (const float*)d_in[6];
    const float* sh_down = (const float*)d_in[7];
    float* y = (float*)d_out;

    char* wsb = (char*)d_ws;
    int*   cnt      = (int*)(wsb + 0);                       // 64 ints
    int*   tok_of   = (int*)(wsb + 512);                     // 64*512 ints
    int*   slot_enc = (int*)(wsb + 512 + 131072);            // 2048*6 ints
    float* tw       = (float*)(wsb + 512 + 131072 + 49152);  // 2048*6 floats
    u16*   act      = (u16*)(wsb + 230144);                  // 64*512*1408 bf16
    u16*   actsh    = (u16*)(wsb + 230144 + 92274688);       // 2048*2816 bf16
    u16*   dbuf     = (u16*)(wsb + 230144 + 92274688 + 11534336); // 64*512*2048 bf16
    u16*   xbf      = dbuf;  // alias: xbf (8MB) dead before down_gemm writes dbuf

    init_cnt<<<1, 64, 0, stream>>>(cnt);
    xcvt<<<NTOK * H / 8 / 256, 256, 0, stream>>>(x, xbf);
    gate_topk<<<NTOK, 64, 0, stream>>>(x, gw, cnt, tok_of, slot_enc, tw);
    dual_gemm<true><<<dim3(FDIM / 32, 2, NE), 256, 0, stream>>>(
        xbf, tok_of, cnt, w_gate, w_up, act, FDIM);
    dual_gemm<false><<<dim3(NTOK / 256, FSH / 32, 1), 256, 0, stream>>>(
        xbf, nullptr, nullptr, sh_gate, sh_up, actsh, FSH);
    down_gemm<true><<<dim3(H / 64, 2, NE), 256, 0, stream>>>(
        act, w_down, (void*)dbuf, cnt, FDIM);
    down_gemm<false><<<dim3(NTOK / 256, H / 64, 1), 256, 0, stream>>>(
        actsh, sh_down, (void*)y, nullptr, FSH);
    combine<<<NTOK, 256, 0, stream>>>(y, dbuf, slot_enc, tw);
}

// Round 6
// 998.138 us; speedup vs baseline: 1.4679x; 1.3303x over previous
//
#include <hip/hip_runtime.h>
#include <hip/hip_bf16.h>

#define H 2048
#define FDIM 1408
#define NE 64
#define CAP 512
#define NTOK 2048
#define FSH 2816

typedef float  f32x4  __attribute__((ext_vector_type(4)));
typedef short  s16x8  __attribute__((ext_vector_type(8)));
typedef unsigned short u16;
typedef u16    u16x4v __attribute__((ext_vector_type(4)));

__device__ __forceinline__ u16 f2bf(float f) {
    union { float f; unsigned u; } v; v.f = f;
    unsigned u = v.u;
    u += 0x7fffu + ((u >> 16) & 1u);
    return (u16)(u >> 16);
}
__device__ __forceinline__ float bf2f(u16 b) {
    union { unsigned u; float f; } v; v.u = ((unsigned)b) << 16;
    return v.f;
}
// element-granular XOR swizzle (multiples of 8 elems = 16B) within 64-elem rows
__device__ __forceinline__ int swze(int row) {
    return (((row & 7) ^ ((row >> 3) & 7)) << 3);
}
__device__ __forceinline__ void wr4(u16* dst, float a, float b, float c, float d) {
    u16x4v v; v[0] = f2bf(a); v[1] = f2bf(b); v[2] = f2bf(c); v[3] = f2bf(d);
    *(u16x4v*)dst = v;
}
__device__ __forceinline__ void glds16(const u16* g, u16* l) {
    __builtin_amdgcn_global_load_lds(
        (const __attribute__((address_space(1))) unsigned int*)g,
        (__attribute__((address_space(3))) unsigned int*)l, 16, 0, 0);
}

// barrier that does NOT drain vmcnt
#define BAR() do { asm volatile("s_waitcnt lgkmcnt(0)" ::: "memory"); \
                   __builtin_amdgcn_s_barrier(); } while (0)
#define WAIT_VM(N)  asm volatile("s_waitcnt vmcnt(" #N ")" ::: "memory")
#define SCHED_FENCE() __builtin_amdgcn_sched_barrier(0)

// ---------------- x fp32 -> bf16 once ----------------
__global__ __launch_bounds__(256) void xcvt(const float* __restrict__ x, u16* __restrict__ xb) {
    int i = blockIdx.x * 256 + threadIdx.x;
    const float4 a = ((const float4*)x)[2 * i];
    const float4 b = ((const float4*)x)[2 * i + 1];
    u16 v[8] = { f2bf(a.x), f2bf(a.y), f2bf(a.z), f2bf(a.w),
                 f2bf(b.x), f2bf(b.y), f2bf(b.z), f2bf(b.w) };
    *(s16x8*)(xb + (size_t)i * 8) = *(s16x8*)v;
}

// ---------------- init ----------------
__global__ void init_cnt(int* __restrict__ c) { c[threadIdx.x] = 0; }

// ---------------- gate: logits -> softmax -> top6 -> slot assign ----------------
__global__ __launch_bounds__(64) void gate_topk(
    const float* __restrict__ xg, const float* __restrict__ gw,
    int* __restrict__ cnt, int* __restrict__ tok_of,
    int* __restrict__ slot_enc, float* __restrict__ tw)
{
    const int t = blockIdx.x;
    const int lane = threadIdx.x;
    __shared__ float4 xs[512];
    const float4* xr = (const float4*)(xg + (size_t)t * H);
    #pragma unroll
    for (int i = 0; i < 8; ++i) xs[i * 64 + lane] = xr[i * 64 + lane];
    __syncthreads();

    const float4* gr = (const float4*)(gw + (size_t)lane * H);
    float acc = 0.f;
    #pragma unroll 4
    for (int i = 0; i < 512; ++i) {
        float4 a = xs[i], b = gr[i];
        acc += a.x * b.x + a.y * b.y + a.z * b.z + a.w * b.w;
    }
    float m = acc;
    #pragma unroll
    for (int off = 32; off; off >>= 1) m = fmaxf(m, __shfl_xor(m, off));
    float p = __expf(acc - m);
    float s = p;
    #pragma unroll
    for (int off = 32; off; off >>= 1) s += __shfl_xor(s, off);
    p = p / s;

    float myw = 0.f; int mye = 0;
    float v = p;
    for (int k = 0; k < 6; ++k) {
        float bv = v; int bi = lane;
        #pragma unroll
        for (int off = 32; off; off >>= 1) {
            float ov = __shfl_xor(bv, off);
            int   oi = __shfl_xor(bi, off);
            if (ov > bv || (ov == bv && oi < bi)) { bv = ov; bi = oi; }
        }
        if (lane == k)  { myw = bv; mye = bi; }
        if (lane == bi) v = -1.f;
    }
    if (lane < 6) {
        int slot = atomicAdd(&cnt[mye], 1);
        int enc = -1;
        if (slot < CAP) { tok_of[mye * CAP + slot] = t; enc = mye * CAP + slot; }
        slot_enc[t * 6 + lane] = enc;
        tw[t * 6 + lane] = myw;               // SCALE == 1.0
    }
}

// ---------------- fused gate+up grouped GEMM + SiLU ----------------
// BM=256, BN=32/mat, BK=64. A: glds (coalesced 8 lanes/row, source pre-swizzled),
// double LDS. B: single reg set at depth 2, single LDS. lgkm-only barriers;
// counted vmcnt(4) drains A-glds, leaves B in flight.
template<bool ROUTED>
__global__ __launch_bounds__(256, 2) void dual_gemm(
    const u16* __restrict__ xbf, const int* __restrict__ tok_of,
    const int* __restrict__ cnt_arr, const float* __restrict__ wg,
    const float* __restrict__ wu, u16* __restrict__ act, int Fd)
{
    __shared__ u16 As[2][256 * 64];       // 64 KB
    __shared__ u16 Bgs[32 * 64];          // 4 KB (single buf)
    __shared__ u16 Bus[32 * 64];          // 4 KB

    int e = 0, cnt, m0, f0;
    if constexpr (ROUTED) {
        e = blockIdx.z;
        cnt = cnt_arr[e]; cnt = cnt < CAP ? cnt : CAP;
        f0 = blockIdx.x * 32; m0 = blockIdx.y * 256;
        if (m0 >= cnt) return;
    } else {
        cnt = NTOK;
        m0 = blockIdx.x * 256; f0 = blockIdx.y * 32;
    }

    const float* wg_e = wg;
    const float* wu_e = wu;
    u16* act_e = act;
    if constexpr (ROUTED) {
        wg_e += (size_t)e * H * Fd;
        wu_e += (size_t)e * H * Fd;
        act_e += (size_t)e * CAP * Fd;
    }

    const int tid = threadIdx.x;
    const int lane = tid & 63;
    const int wv = tid >> 6;
    const int NT = H / 64;                // 32

    // ---- A glds geometry: chunk it covers rows it*32 + wv*8 .. +7 ----
    // lane l -> row it*32 + wv*8 + (l>>3), global col granule pre-swizzled so
    // that linear LDS == read-side XOR layout.
    const u16* agp[8];
    #pragma unroll
    for (int it = 0; it < 8; ++it) {
        int rloc = it * 32 + wv * 8 + (lane >> 3);
        int srow = m0 + rloc;
        int gcol = (((lane & 7) ^ (lane >> 3) ^ ((it * 4 + wv) & 7)) << 3);
        const u16* base;
        if constexpr (ROUTED) {
            const int* tok = tok_of + e * CAP;
            base = xbf + (size_t)tok[srow < cnt ? srow : 0] * H;
        } else {
            base = xbf + (size_t)srow * H;
        }
        agp[it] = base + gcol;
    }
    // ---- B geometry ----
    const int mat = tid >> 7;
    const int bb = tid & 127;
    const float* bsrc;
    int bn4 = 0, bkb = 0, br = 0, bc = 0;
    if constexpr (ROUTED) {
        bn4 = bb & 7; bkb = bb >> 3;               // 4x4 transpose block
        bsrc = (mat ? wu_e : wg_e) + (size_t)(bkb * 4) * Fd + f0 + bn4 * 4;
    } else {
        br = bb >> 2; bc = bb & 3;                 // direct row, 16 floats/thread
        bsrc = (mat ? wu_e : wg_e) + (size_t)(f0 + br) * H + bc * 16;
    }

    f32x4 accg[4][2], accu[4][2];
    const f32x4 zero4 = {0.f, 0.f, 0.f, 0.f};
    #pragma unroll
    for (int i = 0; i < 4; ++i)
        #pragma unroll
        for (int j = 0; j < 2; ++j) { accg[i][j] = zero4; accu[i][j] = zero4; }

    f32x4 bR[4];

    auto GLDS_A = [&](int kt, int b) {
        #pragma unroll
        for (int it = 0; it < 8; ++it)
            glds16(agp[it] + kt * 64, &As[b][(it * 32 + wv * 8) * 64]);
    };
    auto LOADB = [&](int kt) {
        if constexpr (ROUTED) {
            #pragma unroll
            for (int j = 0; j < 4; ++j)
                bR[j] = *(const f32x4*)(bsrc + ((size_t)kt * 64 + j) * Fd);
        } else {
            #pragma unroll
            for (int q = 0; q < 4; ++q)
                bR[q] = *(const f32x4*)(bsrc + kt * 64 + q * 4);
        }
    };
    auto STOREB = [&]() {
        u16* Bdst = mat ? Bus : Bgs;
        if constexpr (ROUTED) {
            #pragma unroll
            for (int j = 0; j < 4; ++j) {
                int rr = bn4 * 4 + j;
                wr4(&Bdst[rr * 64 + ((bkb * 4) ^ swze(rr))],
                    bR[0][j], bR[1][j], bR[2][j], bR[3][j]);
            }
        } else {
            #pragma unroll
            for (int q = 0; q < 4; ++q)
                wr4(&Bdst[br * 64 + ((bc * 16 + q * 4) ^ swze(br))],
                    bR[q].x, bR[q].y, bR[q].z, bR[q].w);
        }
    };
    auto COMPUTE = [&](int b) {
        __builtin_amdgcn_s_setprio(1);
        #pragma unroll
        for (int kk = 0; kk < 2; ++kk) {
            const int ko = kk * 32 + (lane >> 4) * 8;
            s16x8 a[4], bg[2], bu[2];
            #pragma unroll
            for (int mi = 0; mi < 4; ++mi) {
                int r = wv * 64 + mi * 16 + (lane & 15);
                a[mi] = *(const s16x8*)&As[b][r * 64 + (ko ^ swze(r))];
            }
            #pragma unroll
            for (int ni = 0; ni < 2; ++ni) {
                int r = ni * 16 + (lane & 15);
                bg[ni] = *(const s16x8*)&Bgs[r * 64 + (ko ^ swze(r))];
                bu[ni] = *(const s16x8*)&Bus[r * 64 + (ko ^ swze(r))];
            }
            #pragma unroll
            for (int mi = 0; mi < 4; ++mi)
                #pragma unroll
                for (int ni = 0; ni < 2; ++ni) {
                    accg[mi][ni] = __builtin_amdgcn_mfma_f32_16x16x32_bf16(a[mi], bg[ni], accg[mi][ni], 0, 0, 0);
                    accu[mi][ni] = __builtin_amdgcn_mfma_f32_16x16x32_bf16(a[mi], bu[ni], accu[mi][ni], 0, 0, 0);
                }
        }
        __builtin_amdgcn_s_setprio(0);
    };

    // ---- prologue: A(0)->buf0 glds; B(0)->LDS; B(1)->regs ----
    GLDS_A(0, 0); SCHED_FENCE();
    LOADB(0);     SCHED_FENCE();
    STOREB();                       // reg-dep drains B(0) (and A(0) glds, prologue-only)
    LOADB(1);     SCHED_FENCE();
    WAIT_VM(4);
    BAR(); SCHED_FENCE();

    // invariant at iter kt: As[kt&1]=A(kt); Bgs/Bus=B(kt); bR=B(kt+1) in flight/done
    for (int kt = 0; kt < NT; ++kt) {
        const int b = kt & 1;
        if (kt + 1 < NT) GLDS_A(kt + 1, b ^ 1);
        SCHED_FENCE();
        COMPUTE(b);
        BAR();                      // BAR1: everyone done reading Bs
        if (kt + 1 < NT) {
            STOREB();               // B(kt+1) -> Bs (reg-dep wait, ~1 iter cover)
            if (kt + 2 < NT) LOADB(kt + 2);
        }
        SCHED_FENCE();
        if (kt + 1 < NT) {
            if (kt + 2 < NT) { WAIT_VM(4); }   // drain A-glds, keep B in flight
            else             { WAIT_VM(0); }
        }
        BAR(); SCHED_FENCE();       // BAR2
    }

    // ---- epilogue: silu(g)*u -> bf16 act (linear layout) ----
    #pragma unroll
    for (int mi = 0; mi < 4; ++mi)
        #pragma unroll
        for (int ni = 0; ni < 2; ++ni)
            #pragma unroll
            for (int r = 0; r < 4; ++r) {
                int srow = m0 + wv * 64 + mi * 16 + (lane >> 4) * 4 + r;
                if (srow < cnt) {
                    int fc = f0 + ni * 16 + (lane & 15);
                    float g = accg[mi][ni][r], u = accu[mi][ni][r];
                    float aa = (g / (1.f + __expf(-g))) * u;
                    act_e[(size_t)srow * Fd + fc] = f2bf(aa);
                }
            }
}

// ---------------- down-proj grouped GEMM ----------------
// BM=256, BN=64, BK=64. Same pipeline as dual_gemm.
template<bool ROUTED>
__global__ __launch_bounds__(256, 2) void down_gemm(
    const u16* __restrict__ actA, const float* __restrict__ wdn,
    void* __restrict__ outp, const int* __restrict__ cnt_arr, int Kd)
{
    __shared__ u16 As[2][256 * 64];       // 64 KB
    __shared__ u16 Bs[64 * 64];           // 8 KB (single buf)

    int e = 0, cnt, m0, n0;
    if constexpr (ROUTED) {
        e = blockIdx.z;
        cnt = cnt_arr[e]; cnt = cnt < CAP ? cnt : CAP;
        n0 = blockIdx.x * 64; m0 = blockIdx.y * 256;
        if (m0 >= cnt) return;
    } else {
        cnt = NTOK;
        m0 = blockIdx.x * 256; n0 = blockIdx.y * 64;
    }

    const u16* A_e = actA;
    const float* B_e = wdn;
    if constexpr (ROUTED) {
        A_e += (size_t)e * CAP * Kd;
        B_e += (size_t)e * Kd * H;
    }
    const int NT = Kd / 64;               // 22 or 44
    const int tid = threadIdx.x, lane = tid & 63, wv = tid >> 6;

    const u16* agp[8];
    #pragma unroll
    for (int it = 0; it < 8; ++it) {
        int rloc = it * 32 + wv * 8 + (lane >> 3);
        int gcol = (((lane & 7) ^ (lane >> 3) ^ ((it * 4 + wv) & 7)) << 3);
        agp[it] = A_e + (size_t)(m0 + rloc) * Kd + gcol;
    }
    const float* bsrc;
    int bn4 = 0, bkq = 0, dr = 0, dc = 0;
    if constexpr (ROUTED) {
        bn4 = tid & 15; bkq = tid >> 4;
        bsrc = B_e + (size_t)(bkq * 4) * H + n0 + bn4 * 4;
    } else {
        dr = tid >> 2; dc = tid & 3;
        bsrc = B_e + (size_t)(n0 + dr) * FSH + dc * 16;
    }

    f32x4 acc[4][4];
    const f32x4 zero4 = {0.f, 0.f, 0.f, 0.f};
    #pragma unroll
    for (int i = 0; i < 4; ++i)
        #pragma unroll
        for (int j = 0; j < 4; ++j) acc[i][j] = zero4;

    f32x4 bR[4];

    auto GLDS_A = [&](int kt, int b) {
        #pragma unroll
        for (int it = 0; it < 8; ++it)
            glds16(agp[it] + kt * 64, &As[b][(it * 32 + wv * 8) * 64]);
    };
    auto LOADB = [&](int kt) {
        if constexpr (ROUTED) {
            #pragma unroll
            for (int j = 0; j < 4; ++j)
                bR[j] = *(const f32x4*)(bsrc + ((size_t)kt * 64 + j) * H);
        } else {
            #pragma unroll
            for (int q = 0; q < 4; ++q)
                bR[q] = *(const f32x4*)(bsrc + kt * 64 + q * 4);
        }
    };
    auto STOREB = [&]() {
        if constexpr (ROUTED) {
            #pragma unroll
            for (int j = 0; j < 4; ++j) {
                int rr = bn4 * 4 + j;
                wr4(&Bs[rr * 64 + ((bkq * 4) ^ swze(rr))],
                    bR[0][j], bR[1][j], bR[2][j], bR[3][j]);
            }
        } else {
            #pragma unroll
            for (int q = 0; q < 4; ++q)
                wr4(&Bs[dr * 64 + ((dc * 16 + q * 4) ^ swze(dr))],
                    bR[q].x, bR[q].y, bR[q].z, bR[q].w);
        }
    };
    auto COMPUTE = [&](int b) {
        __builtin_amdgcn_s_setprio(1);
        #pragma unroll
        for (int kk = 0; kk < 2; ++kk) {
            const int ko = kk * 32 + (lane >> 4) * 8;
            s16x8 a[4], bf[4];
            #pragma unroll
            for (int mi = 0; mi < 4; ++mi) {
                int r = wv * 64 + mi * 16 + (lane & 15);
                a[mi] = *(const s16x8*)&As[b][r * 64 + (ko ^ swze(r))];
            }
            #pragma unroll
            for (int ni = 0; ni < 4; ++ni) {
                int r = ni * 16 + (lane & 15);
                bf[ni] = *(const s16x8*)&Bs[r * 64 + (ko ^ swze(r))];
            }
            #pragma unroll
            for (int mi = 0; mi < 4; ++mi)
                #pragma unroll
                for (int ni = 0; ni < 4; ++ni)
                    acc[mi][ni] = __builtin_amdgcn_mfma_f32_16x16x32_bf16(a[mi], bf[ni], acc[mi][ni], 0, 0, 0);
        }
        __builtin_amdgcn_s_setprio(0);
    };

    GLDS_A(0, 0); SCHED_FENCE();
    LOADB(0);     SCHED_FENCE();
    STOREB();
    LOADB(1);     SCHED_FENCE();
    WAIT_VM(4);
    BAR(); SCHED_FENCE();

    for (int kt = 0; kt < NT; ++kt) {
        const int b = kt & 1;
        if (kt + 1 < NT) GLDS_A(kt + 1, b ^ 1);
        SCHED_FENCE();
        COMPUTE(b);
        BAR();
        if (kt + 1 < NT) {
            STOREB();
            if (kt + 2 < NT) LOADB(kt + 2);
        }
        SCHED_FENCE();
        if (kt + 1 < NT) {
            if (kt + 2 < NT) { WAIT_VM(4); }
            else             { WAIT_VM(0); }
        }
        BAR(); SCHED_FENCE();
    }

    #pragma unroll
    for (int mi = 0; mi < 4; ++mi)
        #pragma unroll
        for (int ni = 0; ni < 4; ++ni)
            #pragma unroll
            for (int r = 0; r < 4; ++r) {
                int srow = m0 + wv * 64 + mi * 16 + (lane >> 4) * 4 + r;
                if (srow < cnt) {
                    int col = n0 + ni * 16 + (lane & 15);
                    float vv = acc[mi][ni][r];
                    if constexpr (ROUTED)
                        ((u16*)outp)[(size_t)e * CAP * H + (size_t)srow * H + col] = f2bf(vv);
                    else
                        ((float*)outp)[(size_t)srow * H + col] = vv;
                }
            }
}

// ---------------- combine: y += sum_k w_k * d[enc_k] ----------------
__global__ __launch_bounds__(256) void combine(
    float* __restrict__ y, const u16* __restrict__ d,
    const int* __restrict__ slot_enc, const float* __restrict__ tw)
{
    const int t = blockIdx.x, tid = threadIdx.x;
    int enc[6]; float w[6];
    #pragma unroll
    for (int k = 0; k < 6; ++k) {
        enc[k] = slot_enc[t * 6 + k];
        w[k] = tw[t * 6 + k];
    }
    float4* yrow = (float4*)(y + (size_t)t * H);
    #pragma unroll
    for (int it = 0; it < 2; ++it) {
        int h4 = it * 256 + tid;
        float4 acc = yrow[h4];
        #pragma unroll
        for (int k = 0; k < 6; ++k) {
            if (enc[k] >= 0) {
                ushort4 dv = ((const ushort4*)(d + (size_t)enc[k] * H))[h4];
                acc.x += w[k] * bf2f(dv.x);
                acc.y += w[k] * bf2f(dv.y);
                acc.z += w[k] * bf2f(dv.z);
                acc.w += w[k] * bf2f(dv.w);
            }
        }
        yrow[h4] = acc;
    }
}

extern "C" void kernel_launch(void* const* d_in, const int* in_sizes, int n_in,
                              void* d_out, int out_size, void* d_ws, size_t ws_size,
                              hipStream_t stream) {
    const float* x       = (const float*)d_in[0];
    const float* gw      = (const float*)d_in[1];
    const float* w_gate  = (const float*)d_in[2];
    const float* w_up    = (const float*)d_in[3];
    const float* w_down  = (const float*)d_in[4];
    const float* sh_gate = (const float*)d_in[5];
    const float* sh_up   = (const float*)d_in[6];
    const float* sh_down = (const float*)d_in[7];
    float* y = (float*)d_out;

    char* wsb = (char*)d_ws;
    int*   cnt      = (int*)(wsb + 0);                       // 64 ints
    int*   tok_of   = (int*)(wsb + 512);                     // 64*512 ints
    int*   slot_enc = (int*)(wsb + 512 + 131072);            // 2048*6 ints
    float* tw       = (float*)(wsb + 512 + 131072 + 49152);  // 2048*6 floats
    u16*   act      = (u16*)(wsb + 230144);                  // 64*512*1408 bf16
    u16*   actsh    = (u16*)(wsb + 230144 + 92274688);       // 2048*2816 bf16
    u16*   dbuf     = (u16*)(wsb + 230144 + 92274688 + 11534336); // 64*512*2048 bf16
    u16*   xbf      = dbuf;  // alias: xbf (8MB) dead before down_gemm writes dbuf

    init_cnt<<<1, 64, 0, stream>>>(cnt);
    xcvt<<<NTOK * H / 8 / 256, 256, 0, stream>>>(x, xbf);
    gate_topk<<<NTOK, 64, 0, stream>>>(x, gw, cnt, tok_of, slot_enc, tw);
    dual_gemm<true><<<dim3(FDIM / 32, 2, NE), 256, 0, stream>>>(
        xbf, tok_of, cnt, w_gate, w_up, act, FDIM);
    dual_gemm<false><<<dim3(NTOK / 256, FSH / 32, 1), 256, 0, stream>>>(
        xbf, nullptr, nullptr, sh_gate, sh_up, actsh, FSH);
    down_gemm<true><<<dim3(H / 64, 2, NE), 256, 0, stream>>>(
        act, w_down, (void*)dbuf, cnt, FDIM);
    down_gemm<false><<<dim3(NTOK / 256, H / 64, 1), 256, 0, stream>>>(
        actsh, sh_down, (void*)y, nullptr, FSH);
    combine<<<NTOK, 256, 0, stream>>>(y, dbuf, slot_enc, tw);
}